// Round 26
// baseline (534.522 us; speedup 1.0000x reference)
//
#include <hip/hip_runtime.h>
#include <hip/hip_bf16.h>

#define NN 8192
#define DD 256
#define GG 64
#define SS 128
#define D2 128
#define KK 8
#define CL_ITERS 10
#define LDSP 132   // padded row stride: 16B-aligned rows, +4-bank rotation/row

// Stub-named kernel kept so the original mangled symbol exists in the .so.
__global__ void DynamicSubClusteringHead_77592879169750_kernel() {}

__device__ __forceinline__ float dsc_wsum(float v) {
  for (int o = 32; o > 0; o <<= 1) v += __shfl_xor(v, o);
  return v;
}

// feat = relu(LN(x@W1+b1))@W2 + b2 ; 8 rows/block, grid 1024, ~16.6 KB LDS
static __global__ void dsc_mlp(const float* x, const float* W1, const float* b1,
                               const float* ln_g, const float* ln_b,
                               const float* W2, const float* b2, float* feat)
{
  __shared__ float xs[8][DD];
  __shared__ float rs[8][DD];
  __shared__ float red1[8][4];
  __shared__ float red2[8][4];
  const int t = threadIdx.x;
  const int lane = t & 63;
  const int wid = t >> 6;
  const int row0 = blockIdx.x * 8;

  for (int r = 0; r < 8; ++r) xs[r][t] = x[(size_t)(row0 + r) * DD + t];
  __syncthreads();

  float acc[8];
  float bb = b1[t];
  for (int r = 0; r < 8; ++r) acc[r] = bb;
  for (int k = 0; k < DD; ++k) {
    float w = W1[(size_t)k * DD + t];
    for (int r = 0; r < 8; ++r) acc[r] = fmaf(xs[r][k], w, acc[r]);
  }
  for (int r = 0; r < 8; ++r) {
    float s = acc[r];
    for (int o = 32; o > 0; o >>= 1) s += __shfl_xor(s, o);
    if (lane == 0) red1[r][wid] = s;
  }
  __syncthreads();
  float g = ln_g[t];
  float be = ln_b[t];
  float mu[8];
  for (int r = 0; r < 8; ++r)
    mu[r] = (red1[r][0] + red1[r][1] + red1[r][2] + red1[r][3]) * (1.0f / 256.0f);
  for (int r = 0; r < 8; ++r) {
    float d = acc[r] - mu[r];
    float s = d * d;
    for (int o = 32; o > 0; o >>= 1) s += __shfl_xor(s, o);
    if (lane == 0) red2[r][wid] = s;
  }
  __syncthreads();
  for (int r = 0; r < 8; ++r) {
    float var = (red2[r][0] + red2[r][1] + red2[r][2] + red2[r][3]) * (1.0f / 256.0f);
    float hn = (acc[r] - mu[r]) / sqrtf(var + 1e-5f) * g + be;
    rs[r][t] = fmaxf(hn, 0.0f);
  }
  __syncthreads();

  const int j = t & 127;
  const int rb = (t >> 7) * 4;
  float f0 = b2[j];
  float f1 = f0, f2 = f0, f3 = f0;
  for (int k = 0; k < DD; ++k) {
    float w = W2[(size_t)k * D2 + j];
    f0 = fmaf(rs[rb + 0][k], w, f0);
    f1 = fmaf(rs[rb + 1][k], w, f1);
    f2 = fmaf(rs[rb + 2][k], w, f2);
    f3 = fmaf(rs[rb + 3][k], w, f3);
  }
  feat[(size_t)(row0 + rb + 0) * D2 + j] = f0;
  feat[(size_t)(row0 + rb + 1) * D2 + j] = f1;
  feat[(size_t)(row0 + rb + 2) * D2 + j] = f2;
  feat[(size_t)(row0 + rb + 3) * D2 + j] = f3;
}

// dot of two 128-float LDS rows via float4 reads, ascending-d fmaf chain
__device__ __forceinline__ float dsc_dot128(const float* a, const float* b) {
  const float4* a4 = (const float4*)a;
  const float4* b4 = (const float4*)b;
  float s = 0.0f;
#pragma unroll 8
  for (int q = 0; q < D2 / 4; ++q) {
    float4 va = a4[q];
    float4 vb = b4[q];
    s = fmaf(va.x, vb.x, s);
    s = fmaf(va.y, vb.y, s);
    s = fmaf(va.z, vb.z, s);
    s = fmaf(va.w, vb.w, s);
  }
  return s;
}

// per-group clustering; grid 64, block 1024; fg + comp staged in dynamic LDS.
// float4 LDS reads (LDSP=132 keeps rows 16B-aligned, conflict-free);
// 4 barriers/iter (cnt fused into the update loop). Accumulation chains
// keep exact ascending order -> bit-identical partition.
static __global__ __launch_bounds__(1024) void dsc_cluster(
    const float* feat, const float* comp, const float* temp, int* glob)
{
  extern __shared__ float dyn[];
  float* fgs = dyn;                 // [SS][LDSP]
  float* cgs = dyn + SS * LDSP;     // [SS][LDSP]

  __shared__ float Cc[KK][LDSP];
  __shared__ float pM[SS][KK + 1];
  __shared__ float nrm[SS];
  __shared__ float mind[SS];
  __shared__ int   asg[SS];
  __shared__ float cnp[KK][2];      // cn partials (2 waves per k)
  __shared__ float csp[KK][2];      // colsum partials
  __shared__ float candv[2];
  __shared__ int   candi[2];
  __shared__ int   farp;

  const int t = threadIdx.x;
  const int gid = blockIdx.x;
  const float T = temp[0];
  const float* fg = feat + (size_t)gid * SS * D2;
  const float* cgp = comp + (size_t)(gid * SS) * NN + (size_t)gid * SS;

  // stage fg and the group's comp block into LDS (float4 both sides)
  for (int idx = t; idx < SS * (D2 / 4); idx += 1024) {
    int i = idx >> 5, q = idx & 31;
    float4 v = ((const float4*)(fg + (size_t)i * D2))[q];
    *(float4*)(fgs + i * LDSP + q * 4) = v;
  }
  for (int idx = t; idx < SS * (SS / 4); idx += 1024) {
    int i = idx >> 5, q = idx & 31;
    float4 v = ((const float4*)(cgp + (size_t)i * NN))[q];
    *(float4*)(cgs + i * LDSP + q * 4) = v;
  }
  __syncthreads();

  if (t < SS) {
    const float* row = fgs + t * LDSP;
    nrm[t] = dsc_dot128(row, row);
    Cc[0][t] = fgs[t];  // center 0 = row 0
  }
  __syncthreads();

  // farthest-point init; sqrt'd distances exactly like the reference
  if (t < SS) {
    float dot = dsc_dot128(fgs + t * LDSP, fgs);
    mind[t] = sqrtf(fmaxf(nrm[t] + nrm[0] - 2.0f * dot, 0.0f));
  }
  __syncthreads();
  for (int kk = 1; kk < KK; ++kk) {
    // parallel first-index argmax over mind (exact match to serial scan)
    if (t < SS) {
      float v = mind[t];
      int idx = t;
      for (int o = 1; o < 64; o <<= 1) {
        float ov = __shfl_xor(v, o);
        int oi = __shfl_xor(idx, o);
        if (ov > v || (ov == v && oi < idx)) { v = ov; idx = oi; }
      }
      if ((t & 63) == 0) { candv[t >> 6] = v; candi[t >> 6] = idx; }
    }
    __syncthreads();
    if (t == 0) farp = (candv[1] > candv[0]) ? candi[1] : candi[0];
    __syncthreads();
    const int fi = farp;
    if (t < SS) {
      const float* frow = fgs + fi * LDSP;
      Cc[kk][t] = frow[t];
      float dot = dsc_dot128(fgs + t * LDSP, frow);
      float dd = sqrtf(fmaxf(nrm[t] + nrm[fi] - 2.0f * dot, 0.0f));
      if (dd < mind[t]) mind[t] = dd;
    }
    __syncthreads();
  }

  // initial cn partials: (k, d) layout, 64-lane tree per wave
  {
    const int k0 = t >> 7, d0 = t & 127;
    float c = Cc[k0][d0];
    float sq = c * c;
    for (int o = 1; o < 64; o <<= 1) sq += __shfl_xor(sq, o);
    if ((t & 63) == 0) cnp[k0][(t >> 6) & 1] = sq;
  }
  __syncthreads();

  const int ri = t >> 3;        // row for logits/q phases
  const int kc = t & 7;         // center for logits/q phases
  const int kq = t >> 7;        // k for reduction/update phases
  const int dq = t & 127;       // d (or i) for reduction/update phases
  for (int it = 0; it < CL_ITERS; ++it) {
    // B: logits + fused width-8 softmax
    float p;
    {
      float cnk = cnp[kc][0] + cnp[kc][1];
      float s = dsc_dot128(fgs + ri * LDSP, Cc[kc]);
      float lg = -sqrtf(fmaxf(nrm[ri] + cnk - 2.0f * s, 0.0f)) / T;
      float m = lg;
      for (int o = 1; o < 8; o <<= 1) m = fmaxf(m, __shfl_xor(m, o, 8));
      float e = expf(lg - m);
      float es = e;
      for (int o = 1; o < 8; o <<= 1) es += __shfl_xor(es, o, 8);
      p = e / es;
      pM[ri][kc] = p;
    }
    __syncthreads();
    // D: colsum partials (k, i) layout
    {
      float v = pM[dq][kq];
      for (int o = 1; o < 64; o <<= 1) v += __shfl_xor(v, o);
      if ((t & 63) == 0) csp[kq][(t >> 6) & 1] = v;
    }
    __syncthreads();
    // E: q + row-normalize + first-index argmax (p carried in register)
    {
      float cs = csp[kc][0] + csp[kc][1] + 1e-6f;
      const float* crow = cgs + ri * LDSP;
      const float4* c4 = (const float4*)crow;
      float dqv = 0.0f;
#pragma unroll 8
      for (int q4 = 0; q4 < SS / 4; ++q4) {
        float4 v = c4[q4];
        int j = 4 * q4;
        dqv = fmaf(v.x, pM[j + 0][kc], dqv);
        dqv = fmaf(v.y, pM[j + 1][kc], dqv);
        dqv = fmaf(v.z, pM[j + 2][kc], dqv);
        dqv = fmaf(v.w, pM[j + 3][kc], dqv);
      }
      float q = p * expf(-(dqv / cs));
      float rsum = q;
      for (int o = 1; o < 8; o <<= 1) rsum += __shfl_xor(rsum, o, 8);
      rsum += 1e-6f;
      float v = q / rsum;
      int bk = kc;
      for (int o = 1; o < 8; o <<= 1) {
        float ov = __shfl_xor(v, o, 8);
        int ok = __shfl_xor(bk, o, 8);
        if (ov > v || (ov == v && ok < bk)) { v = ov; bk = ok; }
      }
      if (kc == 0) asg[ri] = bk;
    }
    __syncthreads();
    // H: center update with fused count (exact ascending-i predicated sum)
    {
      float s2 = 0.0f;
      int c = 0;
#pragma unroll 4
      for (int i = 0; i < SS; ++i) {
        float v = fgs[i * LDSP + dq];
        if (asg[i] == kq) { s2 += v; ++c; }
      }
      float cNew;
      if (c > 0) {
        cNew = s2 / fmaxf((float)c, 1.0f);
        Cc[kq][dq] = cNew;
      } else {
        cNew = Cc[kq][dq];
      }
      float sq = cNew * cNew;
      for (int o = 1; o < 64; o <<= 1) sq += __shfl_xor(sq, o);
      if ((t & 63) == 0) cnp[kq][(t >> 6) & 1] = sq;
    }
    __syncthreads();
  }

  if (t < SS) glob[gid * SS + t] = asg[t] + gid * KK;
}

// labels: out[0..NN) = (float)glob[i]   -- OUTPUT IS FLOAT32
static __global__ void dsc_labels(const int* glob, float* out)
{
  int i = blockIdx.x * blockDim.x + threadIdx.x;
  if (i < NN) out[i] = (float)glob[i];
}

// P[i][j] = (glob[i]==glob[j]) ? 1.0f : 0.0f ; float4 stores, 8 rows/block.
// Skips f32-element window [e_lo, e_hi) (0,0 = disabled; fallback scratch).
static __global__ void dsc_pmat(const int* glob, float* out,
                                unsigned long long e_lo, unsigned long long e_hi)
{
  __shared__ __align__(8) unsigned short gl16[NN];  // 16 KB
  const int t = threadIdx.x;
  for (int i = t; i < NN; i += 256) gl16[i] = (unsigned short)glob[i];
  __syncthreads();
  const int row0 = blockIdx.x * 8;
  const uint2* gv = (const uint2*)gl16;  // 4 labels per uint2
  for (int r = 0; r < 8; ++r) {
    const int row = row0 + r;
    const unsigned int lab = (unsigned int)gl16[row];
    const unsigned long long ebase =
        (unsigned long long)NN + (unsigned long long)row * NN;
    for (int v = t; v < NN / 4; v += 256) {
      uint2 g4 = gv[v];
      float4 o;
      o.x = ((g4.x & 0xFFFFu) == lab) ? 1.0f : 0.0f;
      o.y = ((g4.x >> 16) == lab) ? 1.0f : 0.0f;
      o.z = ((g4.y & 0xFFFFu) == lab) ? 1.0f : 0.0f;
      o.w = ((g4.y >> 16) == lab) ? 1.0f : 0.0f;
      unsigned long long e = ebase + (unsigned long long)v * 4ull;
      if (!(e < e_hi && e + 4ull > e_lo)) {
        *(float4*)(out + e) = o;
      }
    }
  }
}

// fallback-only: patch the skip window (grid 1; glob snapshot in LDS first)
static __global__ void dsc_fix(const int* glob, float* out,
                               unsigned long long e_lo, unsigned long long e_hi)
{
  __shared__ int gl[NN];  // 32 KB
  const int t = threadIdx.x;
  for (int i = t; i < NN; i += 256) gl[i] = glob[i];
  __syncthreads();
  for (unsigned long long e = e_lo + (unsigned long long)t; e < e_hi; e += 256ull) {
    if (e < (unsigned long long)NN) {
      out[e] = (float)gl[e];
    } else {
      unsigned long long pf = e - (unsigned long long)NN;
      int i = (int)(pf >> 13);
      int j = (int)(pf & 8191ull);
      out[e] = (gl[i] == gl[j]) ? 1.0f : 0.0f;
    }
  }
}

extern "C" void kernel_launch(void* const* d_in, const int* in_sizes, int n_in,
                              void* d_out, int out_size, void* d_ws, size_t ws_size,
                              hipStream_t stream) {
  (void)in_sizes;
  (void)n_in;
  const float* x    = (const float*)d_in[0];
  // d_in[1] = lv_group_ids: unused by the reference computation
  const float* comp = (const float*)d_in[2];
  const float* W1   = (const float*)d_in[3];
  const float* b1   = (const float*)d_in[4];
  const float* ln_g = (const float*)d_in[5];
  const float* ln_b = (const float*)d_in[6];
  const float* W2   = (const float*)d_in[7];
  const float* b2   = (const float*)d_in[8];
  const float* temp = (const float*)d_in[9];

  float* out = (float*)d_out;                       // FLOAT32 output buffer
  char* outc = (char*)d_out;
  const size_t out_bytes  = (size_t)out_size * 4u;  // f32: ~268 MB
  const size_t feat_bytes = (size_t)NN * D2 * 4u;   // 4 MB
  const size_t glob_bytes = (size_t)NN * 4u;        // 32 KB
  const size_t scratch_bytes = feat_bytes + glob_bytes;

  float* feat;
  int* glob;
  unsigned long long e_lo = 0ull, e_hi = 0ull;
  int need_fix = 0;
  if (ws_size >= scratch_bytes) {
    feat = (float*)d_ws;
    glob = (int*)((char*)d_ws + feat_bytes);
  } else {
    // carve from d_out's tail; pmat skips the glob window, dsc_fix patches it
    feat = (float*)(outc + out_bytes - glob_bytes - feat_bytes);
    glob = (int*)(outc + out_bytes - glob_bytes);
    e_lo = (unsigned long long)(out_size - NN);
    e_hi = (unsigned long long)out_size;
    need_fix = 1;
  }

  const size_t dyn_lds = (size_t)(2 * SS * LDSP) * sizeof(float);  // 135168 B

  dsc_mlp<<<NN / 8, 256, 0, stream>>>(x, W1, b1, ln_g, ln_b, W2, b2, feat);
  dsc_cluster<<<GG, 1024, dyn_lds, stream>>>(feat, comp, temp, glob);
  dsc_labels<<<(NN + 255) / 256, 256, 0, stream>>>(glob, out);
  dsc_pmat<<<NN / 8, 256, 0, stream>>>(glob, out, e_lo, e_hi);
  if (need_fix) {
    dsc_fix<<<1, 256, 0, stream>>>(glob, out, e_lo, e_hi);
  }
}

// Round 27
// 280.019 us; speedup vs baseline: 1.9089x; 1.9089x over previous
//
#include <hip/hip_runtime.h>
#include <hip/hip_bf16.h>

#define NN 8192
#define DD 256
#define GG 64
#define SS 128
#define D2 128
#define KK 8
#define CL_ITERS 10
#define LDSP 129   // padded row stride (floats) for bank-conflict-free LDS

// Stub-named kernel kept so the original mangled symbol exists in the .so.
__global__ void DynamicSubClusteringHead_77592879169750_kernel() {}

__device__ __forceinline__ float dsc_wsum(float v) {
  for (int o = 32; o > 0; o >>= 1) v += __shfl_xor(v, o);
  return v;
}

// feat = relu(LN(x@W1+b1))@W2 + b2 ; 8 rows/block, grid 1024, ~16.6 KB LDS
static __global__ void dsc_mlp(const float* x, const float* W1, const float* b1,
                               const float* ln_g, const float* ln_b,
                               const float* W2, const float* b2, float* feat)
{
  __shared__ float xs[8][DD];
  __shared__ float rs[8][DD];
  __shared__ float red1[8][4];
  __shared__ float red2[8][4];
  const int t = threadIdx.x;
  const int lane = t & 63;
  const int wid = t >> 6;
  const int row0 = blockIdx.x * 8;

  for (int r = 0; r < 8; ++r) xs[r][t] = x[(size_t)(row0 + r) * DD + t];
  __syncthreads();

  float acc[8];
  float bb = b1[t];
  for (int r = 0; r < 8; ++r) acc[r] = bb;
  for (int k = 0; k < DD; ++k) {
    float w = W1[(size_t)k * DD + t];
    for (int r = 0; r < 8; ++r) acc[r] = fmaf(xs[r][k], w, acc[r]);
  }
  for (int r = 0; r < 8; ++r) {
    float s = dsc_wsum(acc[r]);
    if (lane == 0) red1[r][wid] = s;
  }
  __syncthreads();
  float g = ln_g[t];
  float be = ln_b[t];
  float mu[8];
  for (int r = 0; r < 8; ++r)
    mu[r] = (red1[r][0] + red1[r][1] + red1[r][2] + red1[r][3]) * (1.0f / 256.0f);
  for (int r = 0; r < 8; ++r) {
    float d = acc[r] - mu[r];
    float s = dsc_wsum(d * d);
    if (lane == 0) red2[r][wid] = s;
  }
  __syncthreads();
  for (int r = 0; r < 8; ++r) {
    float var = (red2[r][0] + red2[r][1] + red2[r][2] + red2[r][3]) * (1.0f / 256.0f);
    float hn = (acc[r] - mu[r]) / sqrtf(var + 1e-5f) * g + be;
    rs[r][t] = fmaxf(hn, 0.0f);
  }
  __syncthreads();

  const int j = t & 127;
  const int rb = (t >> 7) * 4;
  float f0 = b2[j];
  float f1 = f0, f2 = f0, f3 = f0;
  for (int k = 0; k < DD; ++k) {
    float w = W2[(size_t)k * D2 + j];
    f0 = fmaf(rs[rb + 0][k], w, f0);
    f1 = fmaf(rs[rb + 1][k], w, f1);
    f2 = fmaf(rs[rb + 2][k], w, f2);
    f3 = fmaf(rs[rb + 3][k], w, f3);
  }
  feat[(size_t)(row0 + rb + 0) * D2 + j] = f0;
  feat[(size_t)(row0 + rb + 1) * D2 + j] = f1;
  feat[(size_t)(row0 + rb + 2) * D2 + j] = f2;
  feat[(size_t)(row0 + rb + 3) * D2 + j] = f3;
}

// per-group clustering; grid 64, block 1024; fg + comp staged in dynamic LDS.
// 3 phases / 3 barriers per iteration:
//   B: logits + fused width-8 softmax          (writes pM)
//   E: q + colsum-inline + row-norm + argmax   (reads pM, writes asg)
//   H: center update + fused count + cn tree   (reads asg, writes Cc/cnp)
// Dot/sum chains are scalar-LDS, ascending order -> bit-identical partition.
static __global__ __launch_bounds__(1024) void dsc_cluster(
    const float* feat, const float* comp, const float* temp, int* glob)
{
  extern __shared__ float dyn[];
  float* fgs = dyn;                 // [SS][LDSP]
  float* cgs = dyn + SS * LDSP;     // [SS][LDSP]

  __shared__ float Cc[KK][LDSP];
  __shared__ float pM[SS][KK + 1];
  __shared__ float nrm[SS];
  __shared__ float mind[SS];
  __shared__ int   asg[SS];
  __shared__ float cnp[KK][2];      // cn partials (2 waves per k)
  __shared__ float candv[2];
  __shared__ int   candi[2];
  __shared__ int   farp;

  const int t = threadIdx.x;
  const int gid = blockIdx.x;
  const float T = temp[0];
  const float* fg = feat + (size_t)gid * SS * D2;
  const float* cgp = comp + (size_t)(gid * SS) * NN + (size_t)gid * SS;

  // stage fg and the group's comp block into LDS (coalesced)
  for (int idx = t; idx < SS * D2; idx += 1024) {
    int i = idx >> 7, d = idx & 127;
    fgs[i * LDSP + d] = fg[idx];
  }
  for (int idx = t; idx < SS * SS; idx += 1024) {
    int i = idx >> 7, j = idx & 127;
    cgs[i * LDSP + j] = cgp[(size_t)i * NN + j];
  }
  __syncthreads();

  if (t < SS) {
    const float* row = fgs + t * LDSP;
    float s = 0.0f;
#pragma unroll 8
    for (int d = 0; d < D2; ++d) s = fmaf(row[d], row[d], s);
    nrm[t] = s;
    Cc[0][t] = fgs[t];  // center 0 = row 0
  }
  __syncthreads();

  // farthest-point init; sqrt'd distances exactly like the reference
  if (t < SS) {
    const float* row = fgs + t * LDSP;
    const float* frow = fgs;  // row 0
    float dot = 0.0f;
#pragma unroll 8
    for (int d = 0; d < D2; ++d) dot = fmaf(row[d], frow[d], dot);
    mind[t] = sqrtf(fmaxf(nrm[t] + nrm[0] - 2.0f * dot, 0.0f));
  }
  __syncthreads();
  for (int kk = 1; kk < KK; ++kk) {
    // parallel first-index argmax over mind (exact match to serial scan)
    if (t < SS) {
      float v = mind[t];
      int idx = t;
      for (int o = 1; o < 64; o <<= 1) {
        float ov = __shfl_xor(v, o);
        int oi = __shfl_xor(idx, o);
        if (ov > v || (ov == v && oi < idx)) { v = ov; idx = oi; }
      }
      if ((t & 63) == 0) { candv[t >> 6] = v; candi[t >> 6] = idx; }
    }
    __syncthreads();
    if (t == 0) farp = (candv[1] > candv[0]) ? candi[1] : candi[0];
    __syncthreads();
    const int fi = farp;
    if (t < SS) {
      const float* frow = fgs + fi * LDSP;
      Cc[kk][t] = frow[t];
      const float* row = fgs + t * LDSP;
      float dot = 0.0f;
#pragma unroll 8
      for (int d = 0; d < D2; ++d) dot = fmaf(row[d], frow[d], dot);
      float dd = sqrtf(fmaxf(nrm[t] + nrm[fi] - 2.0f * dot, 0.0f));
      if (dd < mind[t]) mind[t] = dd;
    }
    __syncthreads();
  }

  // initial cn partials: (k, d) layout, 64-lane tree per wave
  {
    const int k0 = t >> 7, d0 = t & 127;
    float c = Cc[k0][d0];
    float sq = c * c;
    for (int o = 1; o < 64; o <<= 1) sq += __shfl_xor(sq, o);
    if ((t & 63) == 0) cnp[k0][(t >> 6) & 1] = sq;
  }
  __syncthreads();

  const int ri = t >> 3;        // row for logits/q phases
  const int kc = t & 7;         // center for logits/q phases
  const int kq = t >> 7;        // k for the update phase
  const int dq = t & 127;       // d for the update phase
  for (int it = 0; it < CL_ITERS; ++it) {
    // B: logits + fused width-8 softmax
    float p;
    {
      float cnk = cnp[kc][0] + cnp[kc][1];
      const float* row = fgs + ri * LDSP;
      const float* cen = Cc[kc];
      float s = 0.0f;
#pragma unroll 8
      for (int d = 0; d < D2; ++d) s = fmaf(row[d], cen[d], s);
      float lg = -sqrtf(fmaxf(nrm[ri] + cnk - 2.0f * s, 0.0f)) / T;
      float m = lg;
      for (int o = 1; o < 8; o <<= 1) m = fmaxf(m, __shfl_xor(m, o, 8));
      float e = expf(lg - m);
      float es = e;
      for (int o = 1; o < 8; o <<= 1) es += __shfl_xor(es, o, 8);
      p = e / es;
      pM[ri][kc] = p;
    }
    __syncthreads();
    // E: q + inline colsum (exact ascending) + row-norm + first-index argmax
    {
      const float* crow = cgs + ri * LDSP;
      float csum = 0.0f;
      float dqv = 0.0f;
#pragma unroll 8
      for (int j = 0; j < SS; ++j) {
        float pj = pM[j][kc];
        csum += pj;                       // == reference colsum (ascending i)
        dqv = fmaf(crow[j], pj, dqv);     // == reference cg@p (ascending j)
      }
      float cs = csum + 1e-6f;
      float q = p * expf(-(dqv / cs));
      float rsum = q;
      for (int o = 1; o < 8; o <<= 1) rsum += __shfl_xor(rsum, o, 8);
      rsum += 1e-6f;
      float v = q / rsum;
      int bk = kc;
      for (int o = 1; o < 8; o <<= 1) {
        float ov = __shfl_xor(v, o, 8);
        int ok = __shfl_xor(bk, o, 8);
        if (ov > v || (ov == v && ok < bk)) { v = ov; bk = ok; }
      }
      if (kc == 0) asg[ri] = bk;
    }
    __syncthreads();
    // H: center update + fused count (exact ascending-i) + cn tree
    {
      float s2 = 0.0f;
      int c = 0;
      for (int i = 0; i < SS; ++i) {
        float v = fgs[i * LDSP + dq];
        if (asg[i] == kq) { s2 += v; ++c; }
      }
      float cNew;
      if (c > 0) {
        cNew = s2 / fmaxf((float)c, 1.0f);
        Cc[kq][dq] = cNew;
      } else {
        cNew = Cc[kq][dq];
      }
      float sq = cNew * cNew;
      for (int o = 1; o < 64; o <<= 1) sq += __shfl_xor(sq, o);
      if ((t & 63) == 0) cnp[kq][(t >> 6) & 1] = sq;
    }
    __syncthreads();
  }

  if (t < SS) glob[gid * SS + t] = asg[t] + gid * KK;
}

// labels: out[0..NN) = (float)glob[i]   -- OUTPUT IS FLOAT32
static __global__ void dsc_labels(const int* glob, float* out)
{
  int i = blockIdx.x * blockDim.x + threadIdx.x;
  if (i < NN) out[i] = (float)glob[i];
}

// P[i][j] = (glob[i]==glob[j]) ? 1.0f : 0.0f ; float4 stores, 8 rows/block.
// Skips f32-element window [e_lo, e_hi) (0,0 = disabled; fallback scratch).
static __global__ void dsc_pmat(const int* glob, float* out,
                                unsigned long long e_lo, unsigned long long e_hi)
{
  __shared__ __align__(8) unsigned short gl16[NN];  // 16 KB
  const int t = threadIdx.x;
  for (int i = t; i < NN; i += 256) gl16[i] = (unsigned short)glob[i];
  __syncthreads();
  const int row0 = blockIdx.x * 8;
  const uint2* gv = (const uint2*)gl16;  // 4 labels per uint2
  for (int r = 0; r < 8; ++r) {
    const int row = row0 + r;
    const unsigned int lab = (unsigned int)gl16[row];
    const unsigned long long ebase =
        (unsigned long long)NN + (unsigned long long)row * NN;
    for (int v = t; v < NN / 4; v += 256) {
      uint2 g4 = gv[v];
      float4 o;
      o.x = ((g4.x & 0xFFFFu) == lab) ? 1.0f : 0.0f;
      o.y = ((g4.x >> 16) == lab) ? 1.0f : 0.0f;
      o.z = ((g4.y & 0xFFFFu) == lab) ? 1.0f : 0.0f;
      o.w = ((g4.y >> 16) == lab) ? 1.0f : 0.0f;
      unsigned long long e = ebase + (unsigned long long)v * 4ull;
      if (!(e < e_hi && e + 4ull > e_lo)) {
        *(float4*)(out + e) = o;
      }
    }
  }
}

// fallback-only: patch the skip window (grid 1; glob snapshot in LDS first)
static __global__ void dsc_fix(const int* glob, float* out,
                               unsigned long long e_lo, unsigned long long e_hi)
{
  __shared__ int gl[NN];  // 32 KB
  const int t = threadIdx.x;
  for (int i = t; i < NN; i += 256) gl[i] = glob[i];
  __syncthreads();
  for (unsigned long long e = e_lo + (unsigned long long)t; e < e_hi; e += 256ull) {
    if (e < (unsigned long long)NN) {
      out[e] = (float)gl[e];
    } else {
      unsigned long long pf = e - (unsigned long long)NN;
      int i = (int)(pf >> 13);
      int j = (int)(pf & 8191ull);
      out[e] = (gl[i] == gl[j]) ? 1.0f : 0.0f;
    }
  }
}

extern "C" void kernel_launch(void* const* d_in, const int* in_sizes, int n_in,
                              void* d_out, int out_size, void* d_ws, size_t ws_size,
                              hipStream_t stream) {
  (void)in_sizes;
  (void)n_in;
  const float* x    = (const float*)d_in[0];
  // d_in[1] = lv_group_ids: unused by the reference computation
  const float* comp = (const float*)d_in[2];
  const float* W1   = (const float*)d_in[3];
  const float* b1   = (const float*)d_in[4];
  const float* ln_g = (const float*)d_in[5];
  const float* ln_b = (const float*)d_in[6];
  const float* W2   = (const float*)d_in[7];
  const float* b2   = (const float*)d_in[8];
  const float* temp = (const float*)d_in[9];

  float* out = (float*)d_out;                       // FLOAT32 output buffer
  char* outc = (char*)d_out;
  const size_t out_bytes  = (size_t)out_size * 4u;  // f32: ~268 MB
  const size_t feat_bytes = (size_t)NN * D2 * 4u;   // 4 MB
  const size_t glob_bytes = (size_t)NN * 4u;        // 32 KB
  const size_t scratch_bytes = feat_bytes + glob_bytes;

  float* feat;
  int* glob;
  unsigned long long e_lo = 0ull, e_hi = 0ull;
  int need_fix = 0;
  if (ws_size >= scratch_bytes) {
    feat = (float*)d_ws;
    glob = (int*)((char*)d_ws + feat_bytes);
  } else {
    // carve from d_out's tail; pmat skips the glob window, dsc_fix patches it
    feat = (float*)(outc + out_bytes - glob_bytes - feat_bytes);
    glob = (int*)(outc + out_bytes - glob_bytes);
    e_lo = (unsigned long long)(out_size - NN);
    e_hi = (unsigned long long)out_size;
    need_fix = 1;
  }

  const size_t dyn_lds = (size_t)(2 * SS * LDSP) * sizeof(float);  // 132096 B

  dsc_mlp<<<NN / 8, 256, 0, stream>>>(x, W1, b1, ln_g, ln_b, W2, b2, feat);
  dsc_cluster<<<GG, 1024, dyn_lds, stream>>>(feat, comp, temp, glob);
  dsc_labels<<<(NN + 255) / 256, 256, 0, stream>>>(glob, out);
  dsc_pmat<<<NN / 8, 256, 0, stream>>>(glob, out, e_lo, e_hi);
  if (need_fix) {
    dsc_fix<<<1, 256, 0, stream>>>(glob, out, e_lo, e_hi);
  }
}

// Round 28
// 277.916 us; speedup vs baseline: 1.9233x; 1.0076x over previous
//
#include <hip/hip_runtime.h>
#include <hip/hip_bf16.h>

#define NN 8192
#define DD 256
#define GG 64
#define SS 128
#define D2 128
#define KK 8
#define CL_ITERS 10
#define LDSP 129   // padded row stride (floats) for bank-conflict-free LDS

// Stub-named kernel kept so the original mangled symbol exists in the .so.
__global__ void DynamicSubClusteringHead_77592879169750_kernel() {}

__device__ __forceinline__ float dsc_wsum(float v) {
  for (int o = 32; o > 0; o >>= 1) v += __shfl_xor(v, o);
  return v;
}

// feat = relu(LN(x@W1+b1))@W2 + b2 ; 8 rows/block, grid 1024, ~16.6 KB LDS
static __global__ void dsc_mlp(const float* x, const float* W1, const float* b1,
                               const float* ln_g, const float* ln_b,
                               const float* W2, const float* b2, float* feat)
{
  __shared__ float xs[8][DD];
  __shared__ float rs[8][DD];
  __shared__ float red1[8][4];
  __shared__ float red2[8][4];
  const int t = threadIdx.x;
  const int lane = t & 63;
  const int wid = t >> 6;
  const int row0 = blockIdx.x * 8;

  for (int r = 0; r < 8; ++r) xs[r][t] = x[(size_t)(row0 + r) * DD + t];
  __syncthreads();

  float acc[8];
  float bb = b1[t];
  for (int r = 0; r < 8; ++r) acc[r] = bb;
  for (int k = 0; k < DD; ++k) {
    float w = W1[(size_t)k * DD + t];
    for (int r = 0; r < 8; ++r) acc[r] = fmaf(xs[r][k], w, acc[r]);
  }
  for (int r = 0; r < 8; ++r) {
    float s = dsc_wsum(acc[r]);
    if (lane == 0) red1[r][wid] = s;
  }
  __syncthreads();
  float g = ln_g[t];
  float be = ln_b[t];
  float mu[8];
  for (int r = 0; r < 8; ++r)
    mu[r] = (red1[r][0] + red1[r][1] + red1[r][2] + red1[r][3]) * (1.0f / 256.0f);
  for (int r = 0; r < 8; ++r) {
    float d = acc[r] - mu[r];
    float s = dsc_wsum(d * d);
    if (lane == 0) red2[r][wid] = s;
  }
  __syncthreads();
  for (int r = 0; r < 8; ++r) {
    float var = (red2[r][0] + red2[r][1] + red2[r][2] + red2[r][3]) * (1.0f / 256.0f);
    float hn = (acc[r] - mu[r]) / sqrtf(var + 1e-5f) * g + be;
    rs[r][t] = fmaxf(hn, 0.0f);
  }
  __syncthreads();

  const int j = t & 127;
  const int rb = (t >> 7) * 4;
  float f0 = b2[j];
  float f1 = f0, f2 = f0, f3 = f0;
  for (int k = 0; k < DD; ++k) {
    float w = W2[(size_t)k * D2 + j];
    f0 = fmaf(rs[rb + 0][k], w, f0);
    f1 = fmaf(rs[rb + 1][k], w, f1);
    f2 = fmaf(rs[rb + 2][k], w, f2);
    f3 = fmaf(rs[rb + 3][k], w, f3);
  }
  feat[(size_t)(row0 + rb + 0) * D2 + j] = f0;
  feat[(size_t)(row0 + rb + 1) * D2 + j] = f1;
  feat[(size_t)(row0 + rb + 2) * D2 + j] = f2;
  feat[(size_t)(row0 + rb + 3) * D2 + j] = f3;
}

// per-group clustering; grid 64, block 1024; fg + comp staged in dynamic LDS.
// 3 phases / 3 barriers per iteration. The two hot 128-deep dots use 4-way
// split accumulators (reassociation, +-1ulp; pre-committed revert if the
// partition flips). Other chains stay exact ascending.
static __global__ __launch_bounds__(1024) void dsc_cluster(
    const float* feat, const float* comp, const float* temp, int* glob)
{
  extern __shared__ float dyn[];
  float* fgs = dyn;                 // [SS][LDSP]
  float* cgs = dyn + SS * LDSP;     // [SS][LDSP]

  __shared__ float Cc[KK][LDSP];
  __shared__ float pM[SS][KK + 1];
  __shared__ float nrm[SS];
  __shared__ float mind[SS];
  __shared__ int   asg[SS];
  __shared__ float cnp[KK][2];      // cn partials (2 waves per k)
  __shared__ float candv[2];
  __shared__ int   candi[2];
  __shared__ int   farp;

  const int t = threadIdx.x;
  const int gid = blockIdx.x;
  const float T = temp[0];
  const float* fg = feat + (size_t)gid * SS * D2;
  const float* cgp = comp + (size_t)(gid * SS) * NN + (size_t)gid * SS;

  // stage fg and the group's comp block into LDS (coalesced)
  for (int idx = t; idx < SS * D2; idx += 1024) {
    int i = idx >> 7, d = idx & 127;
    fgs[i * LDSP + d] = fg[idx];
  }
  for (int idx = t; idx < SS * SS; idx += 1024) {
    int i = idx >> 7, j = idx & 127;
    cgs[i * LDSP + j] = cgp[(size_t)i * NN + j];
  }
  __syncthreads();

  if (t < SS) {
    const float* row = fgs + t * LDSP;
    float s = 0.0f;
#pragma unroll 8
    for (int d = 0; d < D2; ++d) s = fmaf(row[d], row[d], s);
    nrm[t] = s;
    Cc[0][t] = fgs[t];  // center 0 = row 0
  }
  __syncthreads();

  // farthest-point init; sqrt'd distances exactly like the reference
  if (t < SS) {
    const float* row = fgs + t * LDSP;
    const float* frow = fgs;  // row 0
    float dot = 0.0f;
#pragma unroll 8
    for (int d = 0; d < D2; ++d) dot = fmaf(row[d], frow[d], dot);
    mind[t] = sqrtf(fmaxf(nrm[t] + nrm[0] - 2.0f * dot, 0.0f));
  }
  __syncthreads();
  for (int kk = 1; kk < KK; ++kk) {
    // parallel first-index argmax over mind (exact match to serial scan)
    if (t < SS) {
      float v = mind[t];
      int idx = t;
      for (int o = 1; o < 64; o <<= 1) {
        float ov = __shfl_xor(v, o);
        int oi = __shfl_xor(idx, o);
        if (ov > v || (ov == v && oi < idx)) { v = ov; idx = oi; }
      }
      if ((t & 63) == 0) { candv[t >> 6] = v; candi[t >> 6] = idx; }
    }
    __syncthreads();
    if (t == 0) farp = (candv[1] > candv[0]) ? candi[1] : candi[0];
    __syncthreads();
    const int fi = farp;
    if (t < SS) {
      const float* frow = fgs + fi * LDSP;
      Cc[kk][t] = frow[t];
      const float* row = fgs + t * LDSP;
      float dot = 0.0f;
#pragma unroll 8
      for (int d = 0; d < D2; ++d) dot = fmaf(row[d], frow[d], dot);
      float dd = sqrtf(fmaxf(nrm[t] + nrm[fi] - 2.0f * dot, 0.0f));
      if (dd < mind[t]) mind[t] = dd;
    }
    __syncthreads();
  }

  // initial cn partials: (k, d) layout, 64-lane tree per wave
  {
    const int k0 = t >> 7, d0 = t & 127;
    float c = Cc[k0][d0];
    float sq = c * c;
    for (int o = 1; o < 64; o <<= 1) sq += __shfl_xor(sq, o);
    if ((t & 63) == 0) cnp[k0][(t >> 6) & 1] = sq;
  }
  __syncthreads();

  const int ri = t >> 3;        // row for logits/q phases
  const int kc = t & 7;         // center for logits/q phases
  const int kq = t >> 7;        // k for the update phase
  const int dq = t & 127;       // d for the update phase
  for (int it = 0; it < CL_ITERS; ++it) {
    // B: logits + fused width-8 softmax (4-way split dot)
    float p;
    {
      float cnk = cnp[kc][0] + cnp[kc][1];
      const float* row = fgs + ri * LDSP;
      const float* cen = Cc[kc];
      float s0 = 0.0f, s1 = 0.0f, s2 = 0.0f, s3 = 0.0f;
#pragma unroll 8
      for (int q = 0; q < D2 / 4; ++q) {
        int d = 4 * q;
        s0 = fmaf(row[d + 0], cen[d + 0], s0);
        s1 = fmaf(row[d + 1], cen[d + 1], s1);
        s2 = fmaf(row[d + 2], cen[d + 2], s2);
        s3 = fmaf(row[d + 3], cen[d + 3], s3);
      }
      float s = (s0 + s1) + (s2 + s3);
      float lg = -sqrtf(fmaxf(nrm[ri] + cnk - 2.0f * s, 0.0f)) / T;
      float m = lg;
      for (int o = 1; o < 8; o <<= 1) m = fmaxf(m, __shfl_xor(m, o, 8));
      float e = expf(lg - m);
      float es = e;
      for (int o = 1; o < 8; o <<= 1) es += __shfl_xor(es, o, 8);
      p = e / es;
      pM[ri][kc] = p;
    }
    __syncthreads();
    // E: q + inline colsum + row-norm + argmax (4-way split chains)
    {
      const float* crow = cgs + ri * LDSP;
      float c0 = 0.0f, c1 = 0.0f, c2 = 0.0f, c3 = 0.0f;
      float d0 = 0.0f, d1 = 0.0f, d2 = 0.0f, d3 = 0.0f;
#pragma unroll 8
      for (int q4 = 0; q4 < SS / 4; ++q4) {
        int j = 4 * q4;
        float p0 = pM[j + 0][kc];
        float p1 = pM[j + 1][kc];
        float p2 = pM[j + 2][kc];
        float p3 = pM[j + 3][kc];
        c0 += p0; c1 += p1; c2 += p2; c3 += p3;
        d0 = fmaf(crow[j + 0], p0, d0);
        d1 = fmaf(crow[j + 1], p1, d1);
        d2 = fmaf(crow[j + 2], p2, d2);
        d3 = fmaf(crow[j + 3], p3, d3);
      }
      float cs = ((c0 + c1) + (c2 + c3)) + 1e-6f;
      float dqv = (d0 + d1) + (d2 + d3);
      float q = p * expf(-(dqv / cs));
      float rsum = q;
      for (int o = 1; o < 8; o <<= 1) rsum += __shfl_xor(rsum, o, 8);
      rsum += 1e-6f;
      float v = q / rsum;
      int bk = kc;
      for (int o = 1; o < 8; o <<= 1) {
        float ov = __shfl_xor(v, o, 8);
        int ok = __shfl_xor(bk, o, 8);
        if (ov > v || (ov == v && ok < bk)) { v = ov; bk = ok; }
      }
      if (kc == 0) asg[ri] = bk;
    }
    __syncthreads();
    // H: center update + fused count (exact ascending-i) + cn tree
    {
      float s2 = 0.0f;
      int c = 0;
      for (int i = 0; i < SS; ++i) {
        float v = fgs[i * LDSP + dq];
        if (asg[i] == kq) { s2 += v; ++c; }
      }
      float cNew;
      if (c > 0) {
        cNew = s2 / fmaxf((float)c, 1.0f);
        Cc[kq][dq] = cNew;
      } else {
        cNew = Cc[kq][dq];
      }
      float sq = cNew * cNew;
      for (int o = 1; o < 64; o <<= 1) sq += __shfl_xor(sq, o);
      if ((t & 63) == 0) cnp[kq][(t >> 6) & 1] = sq;
    }
    __syncthreads();
  }

  if (t < SS) glob[gid * SS + t] = asg[t] + gid * KK;
}

// labels: out[0..NN) = (float)glob[i]   -- OUTPUT IS FLOAT32
static __global__ void dsc_labels(const int* glob, float* out)
{
  int i = blockIdx.x * blockDim.x + threadIdx.x;
  if (i < NN) out[i] = (float)glob[i];
}

// P[i][j] = (glob[i]==glob[j]) ? 1.0f : 0.0f ; float4 stores, 8 rows/block.
// Skips f32-element window [e_lo, e_hi) (0,0 = disabled; fallback scratch).
static __global__ void dsc_pmat(const int* glob, float* out,
                                unsigned long long e_lo, unsigned long long e_hi)
{
  __shared__ __align__(8) unsigned short gl16[NN];  // 16 KB
  const int t = threadIdx.x;
  for (int i = t; i < NN; i += 256) gl16[i] = (unsigned short)glob[i];
  __syncthreads();
  const int row0 = blockIdx.x * 8;
  const uint2* gv = (const uint2*)gl16;  // 4 labels per uint2
  for (int r = 0; r < 8; ++r) {
    const int row = row0 + r;
    const unsigned int lab = (unsigned int)gl16[row];
    const unsigned long long ebase =
        (unsigned long long)NN + (unsigned long long)row * NN;
    for (int v = t; v < NN / 4; v += 256) {
      uint2 g4 = gv[v];
      float4 o;
      o.x = ((g4.x & 0xFFFFu) == lab) ? 1.0f : 0.0f;
      o.y = ((g4.x >> 16) == lab) ? 1.0f : 0.0f;
      o.z = ((g4.y & 0xFFFFu) == lab) ? 1.0f : 0.0f;
      o.w = ((g4.y >> 16) == lab) ? 1.0f : 0.0f;
      unsigned long long e = ebase + (unsigned long long)v * 4ull;
      if (!(e < e_hi && e + 4ull > e_lo)) {
        *(float4*)(out + e) = o;
      }
    }
  }
}

// fallback-only: patch the skip window (grid 1; glob snapshot in LDS first)
static __global__ void dsc_fix(const int* glob, float* out,
                               unsigned long long e_lo, unsigned long long e_hi)
{
  __shared__ int gl[NN];  // 32 KB
  const int t = threadIdx.x;
  for (int i = t; i < NN; i += 256) gl[i] = glob[i];
  __syncthreads();
  for (unsigned long long e = e_lo + (unsigned long long)t; e < e_hi; e += 256ull) {
    if (e < (unsigned long long)NN) {
      out[e] = (float)gl[e];
    } else {
      unsigned long long pf = e - (unsigned long long)NN;
      int i = (int)(pf >> 13);
      int j = (int)(pf & 8191ull);
      out[e] = (gl[i] == gl[j]) ? 1.0f : 0.0f;
    }
  }
}

extern "C" void kernel_launch(void* const* d_in, const int* in_sizes, int n_in,
                              void* d_out, int out_size, void* d_ws, size_t ws_size,
                              hipStream_t stream) {
  (void)in_sizes;
  (void)n_in;
  const float* x    = (const float*)d_in[0];
  // d_in[1] = lv_group_ids: unused by the reference computation
  const float* comp = (const float*)d_in[2];
  const float* W1   = (const float*)d_in[3];
  const float* b1   = (const float*)d_in[4];
  const float* ln_g = (const float*)d_in[5];
  const float* ln_b = (const float*)d_in[6];
  const float* W2   = (const float*)d_in[7];
  const float* b2   = (const float*)d_in[8];
  const float* temp = (const float*)d_in[9];

  float* out = (float*)d_out;                       // FLOAT32 output buffer
  char* outc = (char*)d_out;
  const size_t out_bytes  = (size_t)out_size * 4u;  // f32: ~268 MB
  const size_t feat_bytes = (size_t)NN * D2 * 4u;   // 4 MB
  const size_t glob_bytes = (size_t)NN * 4u;        // 32 KB
  const size_t scratch_bytes = feat_bytes + glob_bytes;

  float* feat;
  int* glob;
  unsigned long long e_lo = 0ull, e_hi = 0ull;
  int need_fix = 0;
  if (ws_size >= scratch_bytes) {
    feat = (float*)d_ws;
    glob = (int*)((char*)d_ws + feat_bytes);
  } else {
    // carve from d_out's tail; pmat skips the glob window, dsc_fix patches it
    feat = (float*)(outc + out_bytes - glob_bytes - feat_bytes);
    glob = (int*)(outc + out_bytes - glob_bytes);
    e_lo = (unsigned long long)(out_size - NN);
    e_hi = (unsigned long long)out_size;
    need_fix = 1;
  }

  const size_t dyn_lds = (size_t)(2 * SS * LDSP) * sizeof(float);  // 132096 B

  dsc_mlp<<<NN / 8, 256, 0, stream>>>(x, W1, b1, ln_g, ln_b, W2, b2, feat);
  dsc_cluster<<<GG, 1024, dyn_lds, stream>>>(feat, comp, temp, glob);
  dsc_labels<<<(NN + 255) / 256, 256, 0, stream>>>(glob, out);
  dsc_pmat<<<NN / 8, 256, 0, stream>>>(glob, out, e_lo, e_hi);
  if (need_fix) {
    dsc_fix<<<1, 256, 0, stream>>>(glob, out, e_lo, e_hi);
  }
}

// Round 29
// 261.324 us; speedup vs baseline: 2.0454x; 1.0635x over previous
//
#include <hip/hip_runtime.h>
#include <hip/hip_bf16.h>

#define NN 8192
#define DD 256
#define GG 64
#define SS 128
#define D2 128
#define KK 8
#define CL_ITERS 10
#define LQ 33   // padded row stride in float4 units (132 floats)

// Stub-named kernel kept so the original mangled symbol exists in the .so.
__global__ void DynamicSubClusteringHead_77592879169750_kernel() {}

__device__ __forceinline__ float dsc_wsum(float v) {
  for (int o = 32; o > 0; o >>= 1) v += __shfl_xor(v, o);
  return v;
}

// feat = relu(LN(x@W1+b1))@W2 + b2 ; 8 rows/block, grid 1024, ~16.6 KB LDS
static __global__ void dsc_mlp(const float* x, const float* W1, const float* b1,
                               const float* ln_g, const float* ln_b,
                               const float* W2, const float* b2, float* feat)
{
  __shared__ float xs[8][DD];
  __shared__ float rs[8][DD];
  __shared__ float red1[8][4];
  __shared__ float red2[8][4];
  const int t = threadIdx.x;
  const int lane = t & 63;
  const int wid = t >> 6;
  const int row0 = blockIdx.x * 8;

  for (int r = 0; r < 8; ++r) xs[r][t] = x[(size_t)(row0 + r) * DD + t];
  __syncthreads();

  float acc[8];
  float bb = b1[t];
  for (int r = 0; r < 8; ++r) acc[r] = bb;
  for (int k = 0; k < DD; ++k) {
    float w = W1[(size_t)k * DD + t];
    for (int r = 0; r < 8; ++r) acc[r] = fmaf(xs[r][k], w, acc[r]);
  }
  for (int r = 0; r < 8; ++r) {
    float s = dsc_wsum(acc[r]);
    if (lane == 0) red1[r][wid] = s;
  }
  __syncthreads();
  float g = ln_g[t];
  float be = ln_b[t];
  float mu[8];
  for (int r = 0; r < 8; ++r)
    mu[r] = (red1[r][0] + red1[r][1] + red1[r][2] + red1[r][3]) * (1.0f / 256.0f);
  for (int r = 0; r < 8; ++r) {
    float d = acc[r] - mu[r];
    float s = dsc_wsum(d * d);
    if (lane == 0) red2[r][wid] = s;
  }
  __syncthreads();
  for (int r = 0; r < 8; ++r) {
    float var = (red2[r][0] + red2[r][1] + red2[r][2] + red2[r][3]) * (1.0f / 256.0f);
    float hn = (acc[r] - mu[r]) / sqrtf(var + 1e-5f) * g + be;
    rs[r][t] = fmaxf(hn, 0.0f);
  }
  __syncthreads();

  const int j = t & 127;
  const int rb = (t >> 7) * 4;
  float f0 = b2[j];
  float f1 = f0, f2 = f0, f3 = f0;
  for (int k = 0; k < DD; ++k) {
    float w = W2[(size_t)k * D2 + j];
    f0 = fmaf(rs[rb + 0][k], w, f0);
    f1 = fmaf(rs[rb + 1][k], w, f1);
    f2 = fmaf(rs[rb + 2][k], w, f2);
    f3 = fmaf(rs[rb + 3][k], w, f3);
  }
  feat[(size_t)(row0 + rb + 0) * D2 + j] = f0;
  feat[(size_t)(row0 + rb + 1) * D2 + j] = f1;
  feat[(size_t)(row0 + rb + 2) * D2 + j] = f2;
  feat[(size_t)(row0 + rb + 3) * D2 + j] = f3;
}

// 4-component-split dot of two [LQ]-float4 LDS rows (index partition matches
// the r28 split-accumulator form; +-1ulp reassociation, accepted)
__device__ __forceinline__ float dsc_dot4(const float4* a, const float4* b) {
  float s0 = 0.0f, s1 = 0.0f, s2 = 0.0f, s3 = 0.0f;
#pragma unroll 8
  for (int q = 0; q < D2 / 4; ++q) {
    float4 va = a[q];
    float4 vb = b[q];
    s0 = fmaf(va.x, vb.x, s0);
    s1 = fmaf(va.y, vb.y, s1);
    s2 = fmaf(va.z, vb.z, s2);
    s3 = fmaf(va.w, vb.w, s3);
  }
  return (s0 + s1) + (s2 + s3);
}

// per-group clustering; grid 64, block 1024; all hot LDS natively float4
// (ds_read_b128 codegen, no pointer reinterprets on LDS). 3 barrier phases
// per iteration. Per-column center sums stay exact ascending-i.
static __global__ __launch_bounds__(1024) void dsc_cluster(
    const float* feat, const float* comp, const float* temp, int* glob)
{
  extern __shared__ float4 dyn4[];
  float4* fgs4 = dyn4;              // [SS][LQ]
  float4* cgs4 = dyn4 + SS * LQ;    // [SS][LQ]

  __shared__ float4 Cc4[KK][LQ];
  __shared__ float pM[SS][KK + 1];
  __shared__ float nrm[SS];
  __shared__ float mind[SS];
  __shared__ int   asg[SS];
  __shared__ float cnp[KK];
  __shared__ float candv[2];
  __shared__ int   candi[2];
  __shared__ int   farp;

  const int t = threadIdx.x;
  const int gid = blockIdx.x;
  const float T = temp[0];
  const float* fg = feat + (size_t)gid * SS * D2;
  const float* cgp = comp + (size_t)(gid * SS) * NN + (size_t)gid * SS;

  // stage fg and the group's comp block into LDS (float4 global reads)
  for (int idx = t; idx < SS * 32; idx += 1024) {
    int i = idx >> 5, q = idx & 31;
    fgs4[i * LQ + q] = ((const float4*)(fg + (size_t)i * D2))[q];
    cgs4[i * LQ + q] = ((const float4*)(cgp + (size_t)i * NN))[q];
  }
  __syncthreads();

  if (t < SS) {
    const float4* row = fgs4 + t * LQ;
    nrm[t] = dsc_dot4(row, row);
  }
  if (t < 32) Cc4[0][t] = fgs4[t];  // center 0 = row 0
  __syncthreads();

  // farthest-point init; sqrt'd distances like the reference
  if (t < SS) {
    float dot = dsc_dot4(fgs4 + t * LQ, fgs4);
    mind[t] = sqrtf(fmaxf(nrm[t] + nrm[0] - 2.0f * dot, 0.0f));
  }
  __syncthreads();
  for (int kk = 1; kk < KK; ++kk) {
    // parallel first-index argmax over mind (exact match to serial scan)
    if (t < SS) {
      float v = mind[t];
      int idx = t;
      for (int o = 1; o < 64; o <<= 1) {
        float ov = __shfl_xor(v, o);
        int oi = __shfl_xor(idx, o);
        if (ov > v || (ov == v && oi < idx)) { v = ov; idx = oi; }
      }
      if ((t & 63) == 0) { candv[t >> 6] = v; candi[t >> 6] = idx; }
    }
    __syncthreads();
    if (t == 0) farp = (candv[1] > candv[0]) ? candi[1] : candi[0];
    __syncthreads();
    const int fi = farp;
    if (t < 32) Cc4[kk][t] = fgs4[fi * LQ + t];
    if (t < SS) {
      float dot = dsc_dot4(fgs4 + t * LQ, fgs4 + fi * LQ);
      float dd = sqrtf(fmaxf(nrm[t] + nrm[fi] - 2.0f * dot, 0.0f));
      if (dd < mind[t]) mind[t] = dd;
    }
    __syncthreads();
  }

  // initial cn: (k, q) layout, 32-lane tree per k
  if (t < KK * 32) {
    int k0 = t >> 5, q0 = t & 31;
    float4 c = Cc4[k0][q0];
    float sq = (c.x * c.x + c.y * c.y) + (c.z * c.z + c.w * c.w);
    for (int o = 1; o < 32; o <<= 1) sq += __shfl_xor(sq, o, 32);
    if (q0 == 0) cnp[k0] = sq;
  }
  __syncthreads();

  const int ri = t >> 3;        // row for logits/q phases
  const int kc = t & 7;         // center for logits/q phases
  const int kq = t >> 5;        // k for the update phase (t < 256)
  const int qq = t & 31;        // float4-column for the update phase
  for (int it = 0; it < CL_ITERS; ++it) {
    // B: logits + fused width-8 softmax (float4 dot)
    float p;
    {
      float cnk = cnp[kc];
      float s = dsc_dot4(fgs4 + ri * LQ, Cc4[kc]);
      float lg = -sqrtf(fmaxf(nrm[ri] + cnk - 2.0f * s, 0.0f)) / T;
      float m = lg;
      for (int o = 1; o < 8; o <<= 1) m = fmaxf(m, __shfl_xor(m, o, 8));
      float e = expf(lg - m);
      float es = e;
      for (int o = 1; o < 8; o <<= 1) es += __shfl_xor(es, o, 8);
      p = e / es;
      pM[ri][kc] = p;
    }
    __syncthreads();
    // E: q + inline colsum + row-norm + argmax (float4 crow, split chains)
    {
      const float4* crow = cgs4 + ri * LQ;
      float c0 = 0.0f, c1 = 0.0f, c2 = 0.0f, c3 = 0.0f;
      float d0 = 0.0f, d1 = 0.0f, d2 = 0.0f, d3 = 0.0f;
#pragma unroll 8
      for (int q4 = 0; q4 < 32; ++q4) {
        float4 v = crow[q4];
        int j = 4 * q4;
        float p0 = pM[j + 0][kc];
        float p1 = pM[j + 1][kc];
        float p2 = pM[j + 2][kc];
        float p3 = pM[j + 3][kc];
        c0 += p0; c1 += p1; c2 += p2; c3 += p3;
        d0 = fmaf(v.x, p0, d0);
        d1 = fmaf(v.y, p1, d1);
        d2 = fmaf(v.z, p2, d2);
        d3 = fmaf(v.w, p3, d3);
      }
      float cs = ((c0 + c1) + (c2 + c3)) + 1e-6f;
      float dqv = (d0 + d1) + (d2 + d3);
      float q = p * expf(-(dqv / cs));
      float rsum = q;
      for (int o = 1; o < 8; o <<= 1) rsum += __shfl_xor(rsum, o, 8);
      rsum += 1e-6f;
      float v = q / rsum;
      int bk = kc;
      for (int o = 1; o < 8; o <<= 1) {
        float ov = __shfl_xor(v, o, 8);
        int ok = __shfl_xor(bk, o, 8);
        if (ov > v || (ov == v && ok < bk)) { v = ov; bk = ok; }
      }
      if (kc == 0) asg[ri] = bk;
    }
    __syncthreads();
    // H: center update, (k, q) layout, float4 rows; per-column sums exact
    if (t < KK * 32) {
      float4 s = make_float4(0.0f, 0.0f, 0.0f, 0.0f);
      int c = 0;
      for (int i = 0; i < SS; ++i) {
        float4 v = fgs4[i * LQ + qq];
        if (asg[i] == kq) {
          s.x += v.x; s.y += v.y; s.z += v.z; s.w += v.w;
          ++c;
        }
      }
      float4 cNew;
      if (c > 0) {
        float inv = 1.0f / fmaxf((float)c, 1.0f);
        cNew.x = s.x * inv; cNew.y = s.y * inv;
        cNew.z = s.z * inv; cNew.w = s.w * inv;
        Cc4[kq][qq] = cNew;
      } else {
        cNew = Cc4[kq][qq];
      }
      float sq = (cNew.x * cNew.x + cNew.y * cNew.y) +
                 (cNew.z * cNew.z + cNew.w * cNew.w);
      for (int o = 1; o < 32; o <<= 1) sq += __shfl_xor(sq, o, 32);
      if (qq == 0) cnp[kq] = sq;
    }
    __syncthreads();
  }

  if (t < SS) glob[gid * SS + t] = asg[t] + gid * KK;
}

// labels: out[0..NN) = (float)glob[i]   -- OUTPUT IS FLOAT32
static __global__ void dsc_labels(const int* glob, float* out)
{
  int i = blockIdx.x * blockDim.x + threadIdx.x;
  if (i < NN) out[i] = (float)glob[i];
}

// P[i][j] = (glob[i]==glob[j]) ? 1.0f : 0.0f ; float4 stores, 8 rows/block.
// Skips f32-element window [e_lo, e_hi) (0,0 = disabled; fallback scratch).
static __global__ void dsc_pmat(const int* glob, float* out,
                                unsigned long long e_lo, unsigned long long e_hi)
{
  __shared__ __align__(8) unsigned short gl16[NN];  // 16 KB
  const int t = threadIdx.x;
  for (int i = t; i < NN; i += 256) gl16[i] = (unsigned short)glob[i];
  __syncthreads();
  const int row0 = blockIdx.x * 8;
  const uint2* gv = (const uint2*)gl16;  // 4 labels per uint2
  for (int r = 0; r < 8; ++r) {
    const int row = row0 + r;
    const unsigned int lab = (unsigned int)gl16[row];
    const unsigned long long ebase =
        (unsigned long long)NN + (unsigned long long)row * NN;
    for (int v = t; v < NN / 4; v += 256) {
      uint2 g4 = gv[v];
      float4 o;
      o.x = ((g4.x & 0xFFFFu) == lab) ? 1.0f : 0.0f;
      o.y = ((g4.x >> 16) == lab) ? 1.0f : 0.0f;
      o.z = ((g4.y & 0xFFFFu) == lab) ? 1.0f : 0.0f;
      o.w = ((g4.y >> 16) == lab) ? 1.0f : 0.0f;
      unsigned long long e = ebase + (unsigned long long)v * 4ull;
      if (!(e < e_hi && e + 4ull > e_lo)) {
        *(float4*)(out + e) = o;
      }
    }
  }
}

// fallback-only: patch the skip window (grid 1; glob snapshot in LDS first)
static __global__ void dsc_fix(const int* glob, float* out,
                               unsigned long long e_lo, unsigned long long e_hi)
{
  __shared__ int gl[NN];  // 32 KB
  const int t = threadIdx.x;
  for (int i = t; i < NN; i += 256) gl[i] = glob[i];
  __syncthreads();
  for (unsigned long long e = e_lo + (unsigned long long)t; e < e_hi; e += 256ull) {
    if (e < (unsigned long long)NN) {
      out[e] = (float)gl[e];
    } else {
      unsigned long long pf = e - (unsigned long long)NN;
      int i = (int)(pf >> 13);
      int j = (int)(pf & 8191ull);
      out[e] = (gl[i] == gl[j]) ? 1.0f : 0.0f;
    }
  }
}

extern "C" void kernel_launch(void* const* d_in, const int* in_sizes, int n_in,
                              void* d_out, int out_size, void* d_ws, size_t ws_size,
                              hipStream_t stream) {
  (void)in_sizes;
  (void)n_in;
  const float* x    = (const float*)d_in[0];
  // d_in[1] = lv_group_ids: unused by the reference computation
  const float* comp = (const float*)d_in[2];
  const float* W1   = (const float*)d_in[3];
  const float* b1   = (const float*)d_in[4];
  const float* ln_g = (const float*)d_in[5];
  const float* ln_b = (const float*)d_in[6];
  const float* W2   = (const float*)d_in[7];
  const float* b2   = (const float*)d_in[8];
  const float* temp = (const float*)d_in[9];

  float* out = (float*)d_out;                       // FLOAT32 output buffer
  char* outc = (char*)d_out;
  const size_t out_bytes  = (size_t)out_size * 4u;  // f32: ~268 MB
  const size_t feat_bytes = (size_t)NN * D2 * 4u;   // 4 MB
  const size_t glob_bytes = (size_t)NN * 4u;        // 32 KB
  const size_t scratch_bytes = feat_bytes + glob_bytes;

  float* feat;
  int* glob;
  unsigned long long e_lo = 0ull, e_hi = 0ull;
  int need_fix = 0;
  if (ws_size >= scratch_bytes) {
    feat = (float*)d_ws;
    glob = (int*)((char*)d_ws + feat_bytes);
  } else {
    // carve from d_out's tail; pmat skips the glob window, dsc_fix patches it
    feat = (float*)(outc + out_bytes - glob_bytes - feat_bytes);
    glob = (int*)(outc + out_bytes - glob_bytes);
    e_lo = (unsigned long long)(out_size - NN);
    e_hi = (unsigned long long)out_size;
    need_fix = 1;
  }

  const size_t dyn_lds = (size_t)(2 * SS * LQ) * sizeof(float4);  // 135168 B

  dsc_mlp<<<NN / 8, 256, 0, stream>>>(x, W1, b1, ln_g, ln_b, W2, b2, feat);
  dsc_cluster<<<GG, 1024, dyn_lds, stream>>>(feat, comp, temp, glob);
  dsc_labels<<<(NN + 255) / 256, 256, 0, stream>>>(glob, out);
  dsc_pmat<<<NN / 8, 256, 0, stream>>>(glob, out, e_lo, e_hi);
  if (need_fix) {
    dsc_fix<<<1, 256, 0, stream>>>(glob, out, e_lo, e_hi);
  }
}